// Round 9
// baseline (59.103 us; speedup 1.0000x reference)
//
#include <hip/hip_runtime.h>

// CategorySpecificLinear: out[t] = x[t] @ W[cid[t]] + bias[cid[t]]
// Pipeline (2 dispatches):
//   k_prep: block 0 = deterministic bucketize; [1,tpw] = W transpose->bf16;
//           rest = x cvt->bf16.   (unchanged from R8)
//   k_ggemm: BM=32/BN=128/BK=64, 8 waves/block, depth-2 drain, 4 blocks/CU
//            => 32 waves/CU (hw max). cat->XCD L2 partition.

typedef __attribute__((ext_vector_type(8))) short bf16x8;
typedef __attribute__((ext_vector_type(4))) float f32x4;
typedef __attribute__((ext_vector_type(8))) unsigned short ushort8_t;

__device__ __forceinline__ unsigned short f2bf(float f) {
  unsigned u = __float_as_uint(f);
  u += 0x7FFFu + ((u >> 16) & 1u);   // round-to-nearest-even
  return (unsigned short)(u >> 16);
}

// async global->LDS, 16B per active lane; LDS dest = wave-uniform base + lane*16
__device__ __forceinline__ void gload_lds16(const unsigned short* g, unsigned short* l) {
  __builtin_amdgcn_global_load_lds(
      (const __attribute__((address_space(1))) unsigned int*)g,
      (__attribute__((address_space(3))) unsigned int*)l, 16, 0, 0);
}

#define MAXC 8

// ---- kernel 1: fused prep (unchanged from R8) ----
__global__ void k_prep(const float* __restrict__ W, unsigned short* __restrict__ Wt,
                       int Dd, int Oo,
                       const float* __restrict__ x, unsigned short* __restrict__ xb, int nX,
                       const int* __restrict__ cid, int* __restrict__ counts,
                       int* __restrict__ bucket, int T, int C, int tpw) {
  int b   = blockIdx.x;
  int tid = threadIdx.x;

  if (b == 0) {
    __shared__ int cnt[256][MAXC];
    int tpt = (T + 255) / 256;
    int t0  = tid * tpt;
    int t1  = min(t0 + tpt, T);
    for (int c = 0; c < C; ++c) cnt[tid][c] = 0;
    for (int t = t0; t < t1; ++t) cnt[tid][cid[t]]++;
    __syncthreads();
    if (tid < C) {
      int run = 0;
      for (int t = 0; t < 256; ++t) { int v = cnt[t][tid]; cnt[t][tid] = run; run += v; }
      counts[tid] = run;
    }
    __syncthreads();
    for (int t = t0; t < t1; ++t) {
      int c = cid[t];
      int p = cnt[tid][c]++;
      bucket[c * T + p] = t;
    }
    return;
  }

  if (b > tpw) {  // cvt role
    int i = ((b - tpw - 1) * 256 + tid) * 8;
    if (i >= nX) return;
    float4 a0 = *reinterpret_cast<const float4*>(x + i);
    float4 a1 = *reinterpret_cast<const float4*>(x + i + 4);
    ushort8_t o;
    o[0] = f2bf(a0.x); o[1] = f2bf(a0.y); o[2] = f2bf(a0.z); o[3] = f2bf(a0.w);
    o[4] = f2bf(a1.x); o[5] = f2bf(a1.y); o[6] = f2bf(a1.z); o[7] = f2bf(a1.w);
    *reinterpret_cast<ushort8_t*>(xb + i) = o;
    return;
  }

  // transpose role
  int bb  = b - 1;
  int tpc = (Dd / 64) * (Oo / 64);
  int c   = bb / tpc;
  int rem = bb % tpc;
  int d0  = (rem / (Oo / 64)) * 64;
  int o0  = (rem % (Oo / 64)) * 64;

  __shared__ float t[64][65];
  const float* Wc = W + (size_t)c * Dd * Oo;
#pragma unroll
  for (int p = 0; p < 4; ++p) {
    int chunk = p * 256 + tid;
    int r  = chunk >> 4;
    int cb = chunk & 15;
    float4 v = *reinterpret_cast<const float4*>(Wc + (size_t)(d0 + r) * Oo + o0 + cb * 4);
    t[r][cb * 4 + 0] = v.x; t[r][cb * 4 + 1] = v.y;
    t[r][cb * 4 + 2] = v.z; t[r][cb * 4 + 3] = v.w;
  }
  __syncthreads();
  unsigned short* Wtc = Wt + (size_t)c * Oo * Dd;
#pragma unroll
  for (int p = 0; p < 2; ++p) {
    int chunk = p * 256 + tid;
    int orow = chunk >> 3;
    int dseg = chunk & 7;
    ushort8_t w;
#pragma unroll
    for (int j = 0; j < 8; ++j) w[j] = f2bf(t[dseg * 8 + j][orow]);
    *reinterpret_cast<ushort8_t*>(Wtc + (size_t)(o0 + orow) * Dd + d0 + dseg * 8) = w;
  }
}

// ---- kernel 2: grouped GEMM, 32 waves/CU ----
#define BM 32
#define BN 128
#define BK 64
#define TILE_A (BM * BK)   // 2048 elems = 4KB
#define TILE_B (BN * BK)   // 8192 elems = 16KB

__global__ __launch_bounds__(512, 8) void k_ggemm(
    const unsigned short* __restrict__ xb, const unsigned short* __restrict__ Wt,
    const float* __restrict__ bias, const int* __restrict__ counts,
    const int* __restrict__ bucket, float* __restrict__ out,
    int T, int Dd, int Oo) {
  int c  = blockIdx.x;
  int Mc = counts[c];
  int m0 = blockIdx.z * BM;
  if (m0 >= Mc) return;  // block-uniform exit
  int n0 = blockIdx.y * BN;

  __shared__ __align__(16) unsigned short Al[2][TILE_A];  // 8KB
  __shared__ __align__(16) unsigned short Bl[2][TILE_B];  // 32KB  -> 40KB total, 4 blk/CU

  const int tid  = threadIdx.x;
  const int lane = tid & 63;
  const int wid  = tid >> 6;                 // 0..7; wave-tile = 32 x 16 cols

  const int* buck = bucket + c * T;
  const unsigned short* Wc = Wt + (size_t)c * Oo * Dd;

  // A staging: wave w stages rows [w*4, w*4+4) with lanes 0..31 (16B each).
  // Linear LDS dest; source seg pre-swizzled (seg = (lane&7) ^ (row&7)). [rule 21]
  const unsigned short* aSrc;
  int aOff;
  {
    int row = wid * 4 + (lane >> 3);         // lanes 32..63 compute junk, exec-masked off
    int seg = (lane & 7) ^ (row & 7);
    int mr  = m0 + (row & 31);
    int tok = buck[mr < Mc ? mr : Mc - 1];   // clamp; masked at epilogue
    aSrc = xb + (size_t)tok * Dd + seg * 8;
    aOff = (wid * 4) * BK;
  }
  // B staging: wave w stages rows [w*16 + i*8, +8), i<2.
  const unsigned short* bSrc[2];
  int bOff[2];
#pragma unroll
  for (int i = 0; i < 2; ++i) {
    int row = wid * 16 + i * 8 + (lane >> 3);
    int seg = (lane & 7) ^ (row & 7);
    bSrc[i] = Wc + (size_t)(n0 + row) * Dd + seg * 8;
    bOff[i] = (wid * 16 + i * 8) * BK;
  }

  const f32x4 fzero = {0.f, 0.f, 0.f, 0.f};
  f32x4 acc[2];  // 2 M-frags x 1 N-frag (wave-tile 32x16)
  acc[0] = fzero; acc[1] = fzero;

  const int KT = Dd / BK;  // 16

  // prologue: stage tile 0 into buf 0
  if (lane < 32) gload_lds16(aSrc, &Al[0][aOff]);
#pragma unroll
  for (int i = 0; i < 2; ++i) gload_lds16(bSrc[i], &Bl[0][bOff[i]]);
  asm volatile("s_waitcnt vmcnt(0)" ::: "memory");
  __builtin_amdgcn_sched_barrier(0);
  __builtin_amdgcn_s_barrier();

  for (int kt = 0; kt < KT; ++kt) {
    int cur = kt & 1;
    // issue tile kt+1 into the other buffer (its readers done at last barrier)
    if (kt + 1 < KT) {
      int ko = (kt + 1) * BK;
      int nb = cur ^ 1;
      if (lane < 32) gload_lds16(aSrc + ko, &Al[nb][aOff]);
#pragma unroll
      for (int i = 0; i < 2; ++i) gload_lds16(bSrc[i] + ko, &Bl[nb][bOff[i]]);
    }
    // compute tile kt
#pragma unroll
    for (int kk = 0; kk < 2; ++kk) {
      bf16x8 af[2], bf;
#pragma unroll
      for (int mi = 0; mi < 2; ++mi) {
        int row  = mi * 16 + (lane & 15);
        int slot = (kk * 4 + (lane >> 4)) ^ (row & 7);
        af[mi] = *reinterpret_cast<const bf16x8*>(&Al[cur][row * BK + slot * 8]);
      }
      {
        int row  = wid * 16 + (lane & 15);
        int slot = (kk * 4 + (lane >> 4)) ^ (row & 7);
        bf = *reinterpret_cast<const bf16x8*>(&Bl[cur][row * BK + slot * 8]);
      }
      __builtin_amdgcn_s_setprio(1);
      acc[0] = __builtin_amdgcn_mfma_f32_16x16x32_bf16(af[0], bf, acc[0], 0, 0, 0);
      acc[1] = __builtin_amdgcn_mfma_f32_16x16x32_bf16(af[1], bf, acc[1], 0, 0, 0);
      __builtin_amdgcn_s_setprio(0);
    }
    if (kt + 1 < KT) {
      asm volatile("s_waitcnt vmcnt(0)" ::: "memory");  // next tile landed
      __builtin_amdgcn_sched_barrier(0);
      __builtin_amdgcn_s_barrier();                     // all waves' reads of next buf done
    }
  }

  // epilogue: D layout col=lane&15, row=(lane>>4)*4+r  [m89-verified]
#pragma unroll
  for (int mi = 0; mi < 2; ++mi) {
    int rb = m0 + mi * 16 + (lane >> 4) * 4;
#pragma unroll
    for (int r = 0; r < 4; ++r) {
      int mrow = rb + r;
      if (mrow < Mc) {
        int tok = buck[mrow];
        int col = n0 + wid * 16 + (lane & 15);
        out[(size_t)tok * Oo + col] = acc[mi][r] + bias[c * Oo + col];
      }
    }
  }
}

extern "C" void kernel_launch(void* const* d_in, const int* in_sizes, int n_in,
                              void* d_out, int out_size, void* d_ws, size_t ws_size,
                              hipStream_t stream) {
  const float* x    = (const float*)d_in[0];
  const int*   cid  = (const int*)d_in[1];
  const float* W    = (const float*)d_in[2];
  const float* bias = (const float*)d_in[3];
  float* out = (float*)d_out;

  int T = in_sizes[1];            // 4096
  int D = in_sizes[0] / T;        // 1024
  int O = out_size / T;           // 1024
  int C = in_sizes[3] / O;        // 8

  char* ws = (char*)d_ws;
  int* counts = (int*)ws;                                   // C ints
  int* bucket = (int*)(ws + 64);                            // C*T ints
  unsigned short* xb = (unsigned short*)(ws + 64 + (size_t)C * T * 4);  // T*D bf16
  unsigned short* Wt = xb + (size_t)T * D;                  // C*O*D bf16

  int tpw  = C * (D / 64) * (O / 64);            // 2048 transpose blocks
  int cvtb = (T * D / 8 + 255) / 256;            // 2048 cvt blocks
  k_prep<<<1 + tpw + cvtb, 256, 0, stream>>>(W, Wt, D, O, x, xb, T * D,
                                             cid, counts, bucket, T, C, tpw);
  k_ggemm<<<dim3(C, O / BN, (T + BM - 1) / BM), 512, 0, stream>>>(
      xb, Wt, bias, counts, bucket, out, T, D, O);
}

// Round 10
// 49.013 us; speedup vs baseline: 1.2059x; 1.2059x over previous
//
#include <hip/hip_runtime.h>

// CategorySpecificLinear: out[t] = x[t] @ W[cid[t]] + bias[cid[t]]
// Pipeline (2 dispatches):
//   k_prep: block 0 = deterministic bucketize; [1,tpw] = W transpose->bf16;
//           rest = x cvt->bf16.   (unchanged from R8)
//   k_ggemm: BM=128/BN=128/BK=64, 8 waves/block, depth-3 counted vmcnt(4),
//            96KB LDS (1 block/CU), cat->XCD L2 partition.
//   Rationale: staging-throughput ceiling ~12B/cyc/CU (R3/R8/R9) => maximize
//   BM*BN/(BM+BN) at an evenly-spread grid (~256 blocks = 1/CU).

typedef __attribute__((ext_vector_type(8))) short bf16x8;
typedef __attribute__((ext_vector_type(4))) float f32x4;
typedef __attribute__((ext_vector_type(8))) unsigned short ushort8_t;

__device__ __forceinline__ unsigned short f2bf(float f) {
  unsigned u = __float_as_uint(f);
  u += 0x7FFFu + ((u >> 16) & 1u);   // round-to-nearest-even
  return (unsigned short)(u >> 16);
}

// async global->LDS, 16B per lane; LDS dest = wave-uniform base + lane*16
__device__ __forceinline__ void gload_lds16(const unsigned short* g, unsigned short* l) {
  __builtin_amdgcn_global_load_lds(
      (const __attribute__((address_space(1))) unsigned int*)g,
      (__attribute__((address_space(3))) unsigned int*)l, 16, 0, 0);
}

#define MAXC 8

// ---- kernel 1: fused prep (unchanged from R8) ----
__global__ void k_prep(const float* __restrict__ W, unsigned short* __restrict__ Wt,
                       int Dd, int Oo,
                       const float* __restrict__ x, unsigned short* __restrict__ xb, int nX,
                       const int* __restrict__ cid, int* __restrict__ counts,
                       int* __restrict__ bucket, int T, int C, int tpw) {
  int b   = blockIdx.x;
  int tid = threadIdx.x;

  if (b == 0) {
    __shared__ int cnt[256][MAXC];
    int tpt = (T + 255) / 256;
    int t0  = tid * tpt;
    int t1  = min(t0 + tpt, T);
    for (int c = 0; c < C; ++c) cnt[tid][c] = 0;
    for (int t = t0; t < t1; ++t) cnt[tid][cid[t]]++;
    __syncthreads();
    if (tid < C) {
      int run = 0;
      for (int t = 0; t < 256; ++t) { int v = cnt[t][tid]; cnt[t][tid] = run; run += v; }
      counts[tid] = run;
    }
    __syncthreads();
    for (int t = t0; t < t1; ++t) {
      int c = cid[t];
      int p = cnt[tid][c]++;
      bucket[c * T + p] = t;
    }
    return;
  }

  if (b > tpw) {  // cvt role
    int i = ((b - tpw - 1) * 256 + tid) * 8;
    if (i >= nX) return;
    float4 a0 = *reinterpret_cast<const float4*>(x + i);
    float4 a1 = *reinterpret_cast<const float4*>(x + i + 4);
    ushort8_t o;
    o[0] = f2bf(a0.x); o[1] = f2bf(a0.y); o[2] = f2bf(a0.z); o[3] = f2bf(a0.w);
    o[4] = f2bf(a1.x); o[5] = f2bf(a1.y); o[6] = f2bf(a1.z); o[7] = f2bf(a1.w);
    *reinterpret_cast<ushort8_t*>(xb + i) = o;
    return;
  }

  // transpose role
  int bb  = b - 1;
  int tpc = (Dd / 64) * (Oo / 64);
  int c   = bb / tpc;
  int rem = bb % tpc;
  int d0  = (rem / (Oo / 64)) * 64;
  int o0  = (rem % (Oo / 64)) * 64;

  __shared__ float t[64][65];
  const float* Wc = W + (size_t)c * Dd * Oo;
#pragma unroll
  for (int p = 0; p < 4; ++p) {
    int chunk = p * 256 + tid;
    int r  = chunk >> 4;
    int cb = chunk & 15;
    float4 v = *reinterpret_cast<const float4*>(Wc + (size_t)(d0 + r) * Oo + o0 + cb * 4);
    t[r][cb * 4 + 0] = v.x; t[r][cb * 4 + 1] = v.y;
    t[r][cb * 4 + 2] = v.z; t[r][cb * 4 + 3] = v.w;
  }
  __syncthreads();
  unsigned short* Wtc = Wt + (size_t)c * Oo * Dd;
#pragma unroll
  for (int p = 0; p < 2; ++p) {
    int chunk = p * 256 + tid;
    int orow = chunk >> 3;
    int dseg = chunk & 7;
    ushort8_t w;
#pragma unroll
    for (int j = 0; j < 8; ++j) w[j] = f2bf(t[dseg * 8 + j][orow]);
    *reinterpret_cast<ushort8_t*>(Wtc + (size_t)(o0 + orow) * Dd + d0 + dseg * 8) = w;
  }
}

// ---- kernel 2: grouped GEMM, 128x128 tile, depth-3 counted ----
#define BM 128
#define BN 128
#define BK 64
#define TILE_A (BM * BK)   // 8192 elems = 16KB
#define TILE_B (BN * BK)   // 8192 elems = 16KB

__global__ __launch_bounds__(512) void k_ggemm(
    const unsigned short* __restrict__ xb, const unsigned short* __restrict__ Wt,
    const float* __restrict__ bias, const int* __restrict__ counts,
    const int* __restrict__ bucket, float* __restrict__ out,
    int T, int Dd, int Oo) {
  int c  = blockIdx.x;
  int Mc = counts[c];
  int m0 = blockIdx.z * BM;
  if (m0 >= Mc) return;  // block-uniform exit
  int n0 = blockIdx.y * BN;

  extern __shared__ __align__(16) unsigned short smem[];  // 96KB dynamic
  unsigned short* Al = smem;                 // 3 x TILE_A
  unsigned short* Bl = smem + 3 * TILE_A;    // 3 x TILE_B

  const int tid  = threadIdx.x;
  const int lane = tid & 63;
  const int wid  = tid >> 6;                 // 0..7
  const int wm   = wid >> 1, wn = wid & 1;   // 4x2 waves, each 32x64 of C

  const int* buck = bucket + c * T;
  const unsigned short* Wc = Wt + (size_t)c * Oo * Dd;

  // staging: per wave 2 A-gloads + 2 B-gloads per tile; load i covers rows
  // [wid*16 + i*8, +8). Linear LDS dest; global source seg pre-swizzled
  // (seg = (lane&7) ^ (row&7)) so swizzled ds_read sees linear k. [rule 21]
  const unsigned short* aSrc[2];
  const unsigned short* bSrc[2];
  int aOff[2], bOff[2];  // wave-uniform LDS element offsets
#pragma unroll
  for (int i = 0; i < 2; ++i) {
    int row = wid * 16 + i * 8 + (lane >> 3);
    int seg = (lane & 7) ^ (row & 7);
    int mr  = m0 + row;
    int tok = buck[mr < Mc ? mr : Mc - 1];  // clamp; masked at epilogue
    aSrc[i] = xb + (size_t)tok * Dd + seg * 8;
    aOff[i] = (wid * 16 + i * 8) * BK;
    bSrc[i] = Wc + (size_t)(n0 + row) * Dd + seg * 8;
    bOff[i] = aOff[i];
  }

  const f32x4 fzero = {0.f, 0.f, 0.f, 0.f};
  f32x4 acc[2][4];
#pragma unroll
  for (int i = 0; i < 2; ++i)
#pragma unroll
    for (int j = 0; j < 4; ++j) acc[i][j] = fzero;

  const int KT = Dd / BK;  // 16

  // prologue: issue tiles 0 and 1 (4 gloads each per wave)
#pragma unroll
  for (int t8 = 0; t8 < 2; ++t8) {
    unsigned short* Ab = Al + t8 * TILE_A;
    unsigned short* Bb = Bl + t8 * TILE_B;
    int ko = t8 * BK;
#pragma unroll
    for (int i = 0; i < 2; ++i) {
      gload_lds16(aSrc[i] + ko, Ab + aOff[i]);
      gload_lds16(bSrc[i] + ko, Bb + bOff[i]);
    }
  }

  int cur = 0;
  for (int kt = 0; kt < KT; ++kt) {
    // my prev frag ds_reads drained (buffer being overwritten next is safe after
    // barrier); tile kt's 4 loads landed (4 newer = tile kt+1 may stay in flight)
    asm volatile("s_waitcnt lgkmcnt(0)" ::: "memory");
    if (kt < KT - 1) {
      asm volatile("s_waitcnt vmcnt(4)" ::: "memory");
    } else {
      asm volatile("s_waitcnt vmcnt(0)" ::: "memory");
    }
    __builtin_amdgcn_sched_barrier(0);
    __builtin_amdgcn_s_barrier();
    __builtin_amdgcn_sched_barrier(0);

    if (kt + 2 < KT) {
      int nb = cur + 2; if (nb >= 3) nb -= 3;
      int ko = (kt + 2) * BK;
      unsigned short* An = Al + nb * TILE_A;
      unsigned short* Bn = Bl + nb * TILE_B;
#pragma unroll
      for (int i = 0; i < 2; ++i) {
        gload_lds16(aSrc[i] + ko, An + aOff[i]);
        gload_lds16(bSrc[i] + ko, Bn + bOff[i]);
      }
    }

    const unsigned short* Ac = Al + cur * TILE_A;
    const unsigned short* Bc = Bl + cur * TILE_B;
#pragma unroll
    for (int kk = 0; kk < 2; ++kk) {
      bf16x8 af[2], bf[4];
#pragma unroll
      for (int mi = 0; mi < 2; ++mi) {
        int row  = wm * 32 + mi * 16 + (lane & 15);
        int slot = (kk * 4 + (lane >> 4)) ^ (row & 7);
        af[mi] = *reinterpret_cast<const bf16x8*>(&Ac[row * BK + slot * 8]);
      }
#pragma unroll
      for (int ni = 0; ni < 4; ++ni) {
        int row  = wn * 64 + ni * 16 + (lane & 15);
        int slot = (kk * 4 + (lane >> 4)) ^ (row & 7);
        bf[ni] = *reinterpret_cast<const bf16x8*>(&Bc[row * BK + slot * 8]);
      }
#pragma unroll
      for (int mi = 0; mi < 2; ++mi)
#pragma unroll
        for (int ni = 0; ni < 4; ++ni)
          acc[mi][ni] = __builtin_amdgcn_mfma_f32_16x16x32_bf16(af[mi], bf[ni], acc[mi][ni], 0, 0, 0);
    }
    cur = (cur + 1 == 3) ? 0 : cur + 1;
  }

  // epilogue: D layout col=lane&15, row=(lane>>4)*4+r  [m89-verified]
#pragma unroll
  for (int mi = 0; mi < 2; ++mi) {
    int rb = m0 + wm * 32 + mi * 16 + (lane >> 4) * 4;
#pragma unroll
    for (int r = 0; r < 4; ++r) {
      int mrow = rb + r;
      if (mrow < Mc) {
        int tok = buck[mrow];
        float* orow = out + (size_t)tok * Oo;
#pragma unroll
        for (int ni = 0; ni < 4; ++ni) {
          int col = n0 + wn * 64 + ni * 16 + (lane & 15);
          orow[col] = acc[mi][ni][r] + bias[c * Oo + col];
        }
      }
    }
  }
}

extern "C" void kernel_launch(void* const* d_in, const int* in_sizes, int n_in,
                              void* d_out, int out_size, void* d_ws, size_t ws_size,
                              hipStream_t stream) {
  const float* x    = (const float*)d_in[0];
  const int*   cid  = (const int*)d_in[1];
  const float* W    = (const float*)d_in[2];
  const float* bias = (const float*)d_in[3];
  float* out = (float*)d_out;

  int T = in_sizes[1];            // 4096
  int D = in_sizes[0] / T;        // 1024
  int O = out_size / T;           // 1024
  int C = in_sizes[3] / O;        // 8

  char* ws = (char*)d_ws;
  int* counts = (int*)ws;                                   // C ints
  int* bucket = (int*)(ws + 64);                            // C*T ints
  unsigned short* xb = (unsigned short*)(ws + 64 + (size_t)C * T * 4);  // T*D bf16
  unsigned short* Wt = xb + (size_t)T * D;                  // C*O*D bf16

  int tpw  = C * (D / 64) * (O / 64);            // 2048 transpose blocks
  int cvtb = (T * D / 8 + 255) / 256;            // 2048 cvt blocks
  k_prep<<<1 + tpw + cvtb, 256, 0, stream>>>(W, Wt, D, O, x, xb, T * D,
                                             cid, counts, bucket, T, C, tpw);
  size_t ldsBytes = (size_t)3 * (TILE_A + TILE_B) * sizeof(unsigned short);  // 96KB
  k_ggemm<<<dim3(C, O / BN, (T + BM - 1) / BM), 512, ldsBytes, stream>>>(
      xb, Wt, bias, counts, bucket, out, T, D, O);
}

// Round 11
// 46.739 us; speedup vs baseline: 1.2645x; 1.0486x over previous
//
#include <hip/hip_runtime.h>

// CategorySpecificLinear: out[t] = x[t] @ W[cid[t]] + bias[cid[t]]
// Pipeline (2 dispatches):
//   k_prep: block 0 = deterministic bucketize; [1,tpw] = W transpose->bf16;
//           rest = x cvt->bf16.   (unchanged from R8)
//   k_ggemm: BM=BN=128, BK=64, ONE 1024-thread block (16 waves, 4x4) per tile,
//            depth-3 counted vmcnt(2), 96KB LDS, cat->XCD L2 partition.
//   Model (R8/R9/R10): time = staged_bytes / rate(waves_per_CU);
//   rate saturates ~7 TB/s at >=16 waves/CU. 128^2 minimizes bytes (134MB);
//   16 waves now live in one block since grid is only 256 tiles (1/CU).

typedef __attribute__((ext_vector_type(8))) short bf16x8;
typedef __attribute__((ext_vector_type(4))) float f32x4;
typedef __attribute__((ext_vector_type(8))) unsigned short ushort8_t;

__device__ __forceinline__ unsigned short f2bf(float f) {
  unsigned u = __float_as_uint(f);
  u += 0x7FFFu + ((u >> 16) & 1u);   // round-to-nearest-even
  return (unsigned short)(u >> 16);
}

// async global->LDS, 16B per lane; LDS dest = wave-uniform base + lane*16
__device__ __forceinline__ void gload_lds16(const unsigned short* g, unsigned short* l) {
  __builtin_amdgcn_global_load_lds(
      (const __attribute__((address_space(1))) unsigned int*)g,
      (__attribute__((address_space(3))) unsigned int*)l, 16, 0, 0);
}

#define MAXC 8

// ---- kernel 1: fused prep (unchanged from R8) ----
__global__ void k_prep(const float* __restrict__ W, unsigned short* __restrict__ Wt,
                       int Dd, int Oo,
                       const float* __restrict__ x, unsigned short* __restrict__ xb, int nX,
                       const int* __restrict__ cid, int* __restrict__ counts,
                       int* __restrict__ bucket, int T, int C, int tpw) {
  int b   = blockIdx.x;
  int tid = threadIdx.x;

  if (b == 0) {
    __shared__ int cnt[256][MAXC];
    int tpt = (T + 255) / 256;
    int t0  = tid * tpt;
    int t1  = min(t0 + tpt, T);
    for (int c = 0; c < C; ++c) cnt[tid][c] = 0;
    for (int t = t0; t < t1; ++t) cnt[tid][cid[t]]++;
    __syncthreads();
    if (tid < C) {
      int run = 0;
      for (int t = 0; t < 256; ++t) { int v = cnt[t][tid]; cnt[t][tid] = run; run += v; }
      counts[tid] = run;
    }
    __syncthreads();
    for (int t = t0; t < t1; ++t) {
      int c = cid[t];
      int p = cnt[tid][c]++;
      bucket[c * T + p] = t;
    }
    return;
  }

  if (b > tpw) {  // cvt role
    int i = ((b - tpw - 1) * 256 + tid) * 8;
    if (i >= nX) return;
    float4 a0 = *reinterpret_cast<const float4*>(x + i);
    float4 a1 = *reinterpret_cast<const float4*>(x + i + 4);
    ushort8_t o;
    o[0] = f2bf(a0.x); o[1] = f2bf(a0.y); o[2] = f2bf(a0.z); o[3] = f2bf(a0.w);
    o[4] = f2bf(a1.x); o[5] = f2bf(a1.y); o[6] = f2bf(a1.z); o[7] = f2bf(a1.w);
    *reinterpret_cast<ushort8_t*>(xb + i) = o;
    return;
  }

  // transpose role
  int bb  = b - 1;
  int tpc = (Dd / 64) * (Oo / 64);
  int c   = bb / tpc;
  int rem = bb % tpc;
  int d0  = (rem / (Oo / 64)) * 64;
  int o0  = (rem % (Oo / 64)) * 64;

  __shared__ float t[64][65];
  const float* Wc = W + (size_t)c * Dd * Oo;
#pragma unroll
  for (int p = 0; p < 4; ++p) {
    int chunk = p * 256 + tid;
    int r  = chunk >> 4;
    int cb = chunk & 15;
    float4 v = *reinterpret_cast<const float4*>(Wc + (size_t)(d0 + r) * Oo + o0 + cb * 4);
    t[r][cb * 4 + 0] = v.x; t[r][cb * 4 + 1] = v.y;
    t[r][cb * 4 + 2] = v.z; t[r][cb * 4 + 3] = v.w;
  }
  __syncthreads();
  unsigned short* Wtc = Wt + (size_t)c * Oo * Dd;
#pragma unroll
  for (int p = 0; p < 2; ++p) {
    int chunk = p * 256 + tid;
    int orow = chunk >> 3;
    int dseg = chunk & 7;
    ushort8_t w;
#pragma unroll
    for (int j = 0; j < 8; ++j) w[j] = f2bf(t[dseg * 8 + j][orow]);
    *reinterpret_cast<ushort8_t*>(Wtc + (size_t)(o0 + orow) * Dd + d0 + dseg * 8) = w;
  }
}

// ---- kernel 2: grouped GEMM, 128x128 tile, 16 waves/block ----
#define BM 128
#define BN 128
#define BK 64
#define TILE_A (BM * BK)   // 8192 elems = 16KB
#define TILE_B (BN * BK)   // 8192 elems = 16KB

__global__ __launch_bounds__(1024) void k_ggemm(
    const unsigned short* __restrict__ xb, const unsigned short* __restrict__ Wt,
    const float* __restrict__ bias, const int* __restrict__ counts,
    const int* __restrict__ bucket, float* __restrict__ out,
    int T, int Dd, int Oo) {
  int c  = blockIdx.x;
  int Mc = counts[c];
  int m0 = blockIdx.z * BM;
  if (m0 >= Mc) return;  // block-uniform exit
  int n0 = blockIdx.y * BN;

  extern __shared__ __align__(16) unsigned short smem[];  // 96KB dynamic
  unsigned short* Al = smem;                 // 3 x TILE_A
  unsigned short* Bl = smem + 3 * TILE_A;    // 3 x TILE_B

  const int tid  = threadIdx.x;
  const int lane = tid & 63;
  const int wid  = tid >> 6;                 // 0..15
  const int wm   = wid >> 2, wn = wid & 3;   // 4x4 waves, each 32x32 of C

  const int* buck = bucket + c * T;
  const unsigned short* Wc = Wt + (size_t)c * Oo * Dd;

  // staging: per wave 1 A-gload + 1 B-gload per tile; wave w covers rows
  // [w*8, w*8+8). Linear LDS dest; global source seg pre-swizzled
  // (seg = (lane&7) ^ (row&7)) so swizzled ds_read sees linear k. [rule 21]
  const unsigned short* aSrc;
  const unsigned short* bSrc;
  int sOff;  // wave-uniform LDS element offset (same for A and B)
  {
    int row = wid * 8 + (lane >> 3);
    int seg = (lane & 7) ^ (row & 7);
    int mr  = m0 + row;
    int tok = buck[mr < Mc ? mr : Mc - 1];  // clamp; masked at epilogue
    aSrc = xb + (size_t)tok * Dd + seg * 8;
    bSrc = Wc + (size_t)(n0 + row) * Dd + seg * 8;
    sOff = (wid * 8) * BK;
  }

  const f32x4 fzero = {0.f, 0.f, 0.f, 0.f};
  f32x4 acc[2][2];
#pragma unroll
  for (int i = 0; i < 2; ++i)
#pragma unroll
    for (int j = 0; j < 2; ++j) acc[i][j] = fzero;

  const int KT = Dd / BK;  // 16

  // prologue: issue tiles 0 and 1 (2 gloads each per wave)
#pragma unroll
  for (int t8 = 0; t8 < 2; ++t8) {
    int ko = t8 * BK;
    gload_lds16(aSrc + ko, Al + t8 * TILE_A + sOff);
    gload_lds16(bSrc + ko, Bl + t8 * TILE_B + sOff);
  }

  int cur = 0;
  for (int kt = 0; kt < KT; ++kt) {
    // my prev frag ds_reads drained (so buffer cur+2 is safe for all waves after
    // barrier); tile kt's 2 loads landed (2 newer = tile kt+1 may stay in flight)
    asm volatile("s_waitcnt lgkmcnt(0)" ::: "memory");
    if (kt < KT - 1) {
      asm volatile("s_waitcnt vmcnt(2)" ::: "memory");
    } else {
      asm volatile("s_waitcnt vmcnt(0)" ::: "memory");
    }
    __builtin_amdgcn_sched_barrier(0);
    __builtin_amdgcn_s_barrier();
    __builtin_amdgcn_sched_barrier(0);

    if (kt + 2 < KT) {
      int nb = cur + 2; if (nb >= 3) nb -= 3;
      int ko = (kt + 2) * BK;
      gload_lds16(aSrc + ko, Al + nb * TILE_A + sOff);
      gload_lds16(bSrc + ko, Bl + nb * TILE_B + sOff);
    }

    const unsigned short* Ac = Al + cur * TILE_A;
    const unsigned short* Bc = Bl + cur * TILE_B;
#pragma unroll
    for (int kk = 0; kk < 2; ++kk) {
      bf16x8 af[2], bf[2];
#pragma unroll
      for (int mi = 0; mi < 2; ++mi) {
        int row  = wm * 32 + mi * 16 + (lane & 15);
        int slot = (kk * 4 + (lane >> 4)) ^ (row & 7);
        af[mi] = *reinterpret_cast<const bf16x8*>(&Ac[row * BK + slot * 8]);
      }
#pragma unroll
      for (int ni = 0; ni < 2; ++ni) {
        int row  = wn * 32 + ni * 16 + (lane & 15);
        int slot = (kk * 4 + (lane >> 4)) ^ (row & 7);
        bf[ni] = *reinterpret_cast<const bf16x8*>(&Bc[row * BK + slot * 8]);
      }
#pragma unroll
      for (int mi = 0; mi < 2; ++mi)
#pragma unroll
        for (int ni = 0; ni < 2; ++ni)
          acc[mi][ni] = __builtin_amdgcn_mfma_f32_16x16x32_bf16(af[mi], bf[ni], acc[mi][ni], 0, 0, 0);
    }
    cur = (cur + 1 == 3) ? 0 : cur + 1;
  }

  // epilogue: D layout col=lane&15, row=(lane>>4)*4+r  [m89-verified]
#pragma unroll
  for (int mi = 0; mi < 2; ++mi) {
    int rb = m0 + wm * 32 + mi * 16 + (lane >> 4) * 4;
#pragma unroll
    for (int r = 0; r < 4; ++r) {
      int mrow = rb + r;
      if (mrow < Mc) {
        int tok = buck[mrow];
        float* orow = out + (size_t)tok * Oo;
#pragma unroll
        for (int ni = 0; ni < 2; ++ni) {
          int col = n0 + wn * 32 + ni * 16 + (lane & 15);
          orow[col] = acc[mi][ni][r] + bias[c * Oo + col];
        }
      }
    }
  }
}

extern "C" void kernel_launch(void* const* d_in, const int* in_sizes, int n_in,
                              void* d_out, int out_size, void* d_ws, size_t ws_size,
                              hipStream_t stream) {
  const float* x    = (const float*)d_in[0];
  const int*   cid  = (const int*)d_in[1];
  const float* W    = (const float*)d_in[2];
  const float* bias = (const float*)d_in[3];
  float* out = (float*)d_out;

  int T = in_sizes[1];            // 4096
  int D = in_sizes[0] / T;        // 1024
  int O = out_size / T;           // 1024
  int C = in_sizes[3] / O;        // 8

  char* ws = (char*)d_ws;
  int* counts = (int*)ws;                                   // C ints
  int* bucket = (int*)(ws + 64);                            // C*T ints
  unsigned short* xb = (unsigned short*)(ws + 64 + (size_t)C * T * 4);  // T*D bf16
  unsigned short* Wt = xb + (size_t)T * D;                  // C*O*D bf16

  int tpw  = C * (D / 64) * (O / 64);            // 2048 transpose blocks
  int cvtb = (T * D / 8 + 255) / 256;            // 2048 cvt blocks
  k_prep<<<1 + tpw + cvtb, 256, 0, stream>>>(W, Wt, D, O, x, xb, T * D,
                                             cid, counts, bucket, T, C, tpw);
  size_t ldsBytes = (size_t)3 * (TILE_A + TILE_B) * sizeof(unsigned short);  // 96KB
  k_ggemm<<<dim3(C, O / BN, (T + BM - 1) / BM), 1024, ldsBytes, stream>>>(
      xb, Wt, bias, counts, bucket, out, T, D, O);
}